// Round 10
// baseline (248.724 us; speedup 1.0000x reference)
//
#include <hip/hip_runtime.h>

#define NN 1024
#define NP (NN * NN)
#define NBLK 1024
#define NGRP (NBLK * 16)   // 16384 groups, 2 pairs/group/iter -> 32 iters

typedef float f32x4 __attribute__((ext_vector_type(4)));

__device__ __forceinline__ f32x4 ntld(const float* p) {
  return __builtin_nontemporal_load((const f32x4*)p);
}

// DPP butterfly add within a 16-lane row, pure VALU pipe (no LDS ops):
// xor1 = quad_perm(1,0,3,2)=0xB1, xor2 = quad_perm(2,3,0,1)=0x4E,
// xor7 = row_half_mirror=0x141, xor15 = row_mirror=0x140.
// {1,2,7,15} generates the full 16-lane xor group -> all lanes get the sum.
#define DPP_ADD_STAGE(v, ctrl)                                               \
  {                                                                          \
    const int _t = __builtin_amdgcn_update_dpp(                              \
        0, __float_as_int(v), (ctrl), 0xf, 0xf, true);                       \
    (v) += __int_as_float(_t);                                               \
  }

// ---------------- k1: LayerNorm + GEMV, decoupled form, persistent grid -----
// x_d = rstd*(g_d - mu*A_d) + B_d;  A_d = sum gamma*W, B_d = sum beta*W + b.
// 16 lanes/pair, 8 ch/lane; 2 pairs per group per iter; prefetch next iter.
__global__ __launch_bounds__(256) void k_ln_gemv(
    const float* __restrict__ pairp, const float* __restrict__ gamma,
    const float* __restrict__ beta, const float* __restrict__ W,
    const float* __restrict__ bvec, float* __restrict__ xout)
{
  const int l = threadIdx.x & 15;
  const int group = blockIdx.x * 16 + (threadIdx.x >> 4);

  float ug[8][6], apart[6] = {0, 0, 0, 0, 0, 0}, bpart[6] = {0, 0, 0, 0, 0, 0};
#pragma unroll
  for (int k = 0; k < 2; ++k)
#pragma unroll
    for (int m = 0; m < 4; ++m) {
      const int c = 4 * l + 64 * k + m;
      const int idx = 4 * k + m;
      const float ga = gamma[c], be = beta[c];
#pragma unroll
      for (int d = 0; d < 6; ++d) {
        const float w = W[c * 6 + d];
        ug[idx][d] = ga * w;
        apart[d] += ga * w;
        bpart[d] += be * w;
      }
    }
#pragma unroll
  for (int d = 0; d < 6; ++d)
#pragma unroll
    for (int m = 1; m <= 8; m <<= 1) {
      apart[d] += __shfl_xor(apart[d], m);
      bpart[d] += __shfl_xor(bpart[d], m);
    }
  const float vA = (l == 0) ? apart[0] : (l == 1) ? apart[1] : (l == 2) ? apart[2]
                  : (l == 3) ? apart[3] : (l == 4) ? apart[4] : apart[5];
  float vB = (l == 0) ? bpart[0] : (l == 1) ? bpart[1] : (l == 2) ? bpart[2]
            : (l == 3) ? bpart[3] : (l == 4) ? bpart[4] : bpart[5];
  if (l < 6) vB += bvec[l];

  size_t p = 2 * (size_t)group;
  const float* bp = pairp + p * 128 + 4 * l;
  f32x4 a0 = ntld(bp), b0 = ntld(bp + 64);
  f32x4 a1 = ntld(bp + 128), b1 = ntld(bp + 192);

  for (int it = 0; it < 32; ++it) {
    const size_t pn = p + 2 * NGRP;
    f32x4 na0, nb0, na1, nb1;
    if (it != 31) {  // prefetch next iteration's 4 loads before compute
      const float* nbp = pairp + pn * 128 + 4 * l;
      na0 = ntld(nbp); nb0 = ntld(nbp + 64);
      na1 = ntld(nbp + 128); nb1 = ntld(nbp + 192);
    }

    const float xv0[8] = {a0.x, a0.y, a0.z, a0.w, b0.x, b0.y, b0.z, b0.w};
    const float xv1[8] = {a1.x, a1.y, a1.z, a1.w, b1.x, b1.y, b1.z, b1.w};
    float r[16];
#pragma unroll
    for (int k = 0; k < 16; ++k) r[k] = 0.f;
#pragma unroll
    for (int k = 0; k < 8; ++k) {
      r[0] += xv0[k];
      r[1] = fmaf(xv0[k], xv0[k], r[1]);
      r[8] += xv1[k];
      r[9] = fmaf(xv1[k], xv1[k], r[9]);
#pragma unroll
      for (int d = 0; d < 6; ++d) {
        r[2 + d] = fmaf(xv0[k], ug[k][d], r[2 + d]);
        r[10 + d] = fmaf(xv1[k], ug[k][d], r[10 + d]);
      }
    }
    // 16-lane reduction: 4 DPP stages x 16 independent values, VALU-only
#pragma unroll
    for (int k = 0; k < 16; ++k) DPP_ADD_STAGE(r[k], 0xB1);   // xor 1
#pragma unroll
    for (int k = 0; k < 16; ++k) DPP_ADD_STAGE(r[k], 0x4E);   // xor 2
#pragma unroll
    for (int k = 0; k < 16; ++k) DPP_ADD_STAGE(r[k], 0x141);  // xor 7 (half mirror)
#pragma unroll
    for (int k = 0; k < 16; ++k) DPP_ADD_STAGE(r[k], 0x140);  // xor 15 (mirror)

    if (l < 6) {
      const float mu0 = r[0] * (1.f / 128.f);
      const float var0 = r[1] * (1.f / 128.f) - mu0 * mu0;
      const float rstd0 = rsqrtf(var0 + 1e-5f);
      const float vg0 = (l == 0) ? r[2] : (l == 1) ? r[3] : (l == 2) ? r[4]
                       : (l == 3) ? r[5] : (l == 4) ? r[6] : r[7];
      xout[p * 6 + l] = fmaf(rstd0, vg0 - mu0 * vA, vB);

      const float mu1 = r[8] * (1.f / 128.f);
      const float var1 = r[9] * (1.f / 128.f) - mu1 * mu1;
      const float rstd1 = rsqrtf(var1 + 1e-5f);
      const float vg1 = (l == 0) ? r[10] : (l == 1) ? r[11] : (l == 2) ? r[12]
                       : (l == 3) ? r[13] : (l == 4) ? r[14] : r[15];
      xout[(p + 1) * 6 + l] = fmaf(rstd1, vg1 - mu1 * vA, vB);
    }
    p = pn;
    a0 = na0; b0 = nb0; a1 = na1; b1 = nb1;
  }
}

// ---------------- k_sym: one-shot tiled symmetrize + mask + rowsum -----------
__global__ __launch_bounds__(256) void k_sym(
    const float* __restrict__ x, const int* __restrict__ seq,
    float* __restrict__ xs, float* __restrict__ rowsum)
{
  const int J = blockIdx.x, I = blockIdx.y;
  const int tid = threadIdx.x;
  __shared__ float M[32 * 193];

  const float* mb = x + ((size_t)(J * 32) * NN + I * 32) * 6;
  for (int k = tid; k < 1536; k += 256) {
    const int m = k / 48, f = k % 48;
    const float4 v = *(const float4*)(mb + (size_t)m * (NN * 6) + f * 4);
    float* dst = &M[m * 193 + f * 4];
    dst[0] = v.x; dst[1] = v.y; dst[2] = v.z; dst[3] = v.w;
  }
  __syncthreads();

  float es[4][6];
#pragma unroll
  for (int q = 0; q < 4; ++q) {
    const int e = tid + 256 * q;
    const int r = e >> 5, c = e & 31;
    const int i = I * 32 + r, j = J * 32 + c;
    const int dd = seq[i] - seq[j];
    const bool far = (dd > 3) || (dd < -3);
    const float* own = x + ((size_t)i * NN + j) * 6;
    const float2 o0 = *(const float2*)(own);
    const float2 o1 = *(const float2*)(own + 2);
    const float2 o2 = *(const float2*)(own + 4);
    const float* mr = &M[c * 193 + r * 6];
    float v[6];
    v[0] = far ? 0.5f * (o0.x + mr[0]) : -1000000.f;
    v[1] = far ? 0.5f * (o0.y + mr[1]) : -1000000.f;
    v[2] = far ? 0.5f * (o1.x + mr[2]) : -1000000.f;
    v[3] = far ? 0.5f * (o1.y + mr[3]) : -1000000.f;
    v[4] = far ? 0.5f * (o2.x + mr[4]) : -1000000.f;
    v[5] = far ? 0.5f * (o2.y + mr[5]) : -1000000.f;
    float* op = xs + ((size_t)i * NN + j) * 6;
    *(float2*)(op) = make_float2(v[0], v[1]);
    *(float2*)(op + 2) = make_float2(v[2], v[3]);
    *(float2*)(op + 4) = make_float2(v[4], v[5]);
#pragma unroll
    for (int d = 0; d < 6; ++d) es[q][d] = __expf(v[d]);
  }

#pragma unroll
  for (int q = 0; q < 4; ++q)
#pragma unroll
    for (int d = 0; d < 6; ++d)
#pragma unroll
      for (int m = 1; m <= 16; m <<= 1) es[q][d] += __shfl_xor(es[q][d], m);

  if ((tid & 31) == 0) {
    const int w = tid >> 5;
#pragma unroll
    for (int q = 0; q < 4; ++q) {
      const int i = I * 32 + w + 8 * q;
#pragma unroll
      for (int d = 0; d < 6; ++d) atomicAdd(&rowsum[i * 6 + d], es[q][d]);
    }
  }
}

__global__ __launch_bounds__(256) void k_lse(
    const float* __restrict__ rowsum, float* __restrict__ lse)
{
  const int k = blockIdx.x * 256 + threadIdx.x;
  if (k < NN * 6) lse[k] = logf(1.0f + rowsum[k]);
}

__global__ __launch_bounds__(256) void k_out(
    float* __restrict__ out, const float* __restrict__ lse)
{
  const int p = blockIdx.x * 256 + threadIdx.x;
  const int i = p >> 10;
  const int j = p & (NN - 1);

  float* a = out + (size_t)p * 6;
  const float2 a0 = *(const float2*)(a);
  const float2 a1 = *(const float2*)(a + 2);
  const float2 a2 = *(const float2*)(a + 4);
  const float v[6] = {a0.x, a0.y, a1.x, a1.y, a2.x, a2.y};

  float ssum = 0.f;
#pragma unroll
  for (int d = 0; d < 6; ++d) ssum += __expf(v[d]);
  const float lc2 = 2.f * logf(1.f + ssum);

  const float* li = lse + i * 6;
  const float* lj = lse + j * 6;
  float o[6];
#pragma unroll
  for (int d = 0; d < 6; ++d) o[d] = 4.f * v[d] - li[d] - lj[d] - lc2;

  *(float2*)(a) = make_float2(o[0], o[1]);
  *(float2*)(a + 2) = make_float2(o[2], o[3]);
  *(float2*)(a + 4) = make_float2(o[4], o[5]);
}

extern "C" void kernel_launch(void* const* d_in, const int* in_sizes, int n_in,
                              void* d_out, int out_size, void* d_ws, size_t ws_size,
                              hipStream_t stream) {
  const float* pairp = (const float*)d_in[0];
  const int* seq = (const int*)d_in[1];
  const float* gamma = (const float*)d_in[2];
  const float* beta = (const float*)d_in[3];
  const float* W = (const float*)d_in[4];
  const float* bvec = (const float*)d_in[5];
  float* out = (float*)d_out;

  float* x = (float*)d_ws;              // raw x: 1024*1024*6 fp32 = 24 MB
  float* rowsum = x + (size_t)NP * 6;   // 1024*6
  float* lse = rowsum + NN * 6;         // 1024*6

  (void)hipMemsetAsync(rowsum, 0, NN * 6 * sizeof(float), stream);
  // TIMING BISECTION: k1 launched TWICE (idempotent: x = f(pair), inputs
  // never mutated -> identical result). total - 151us(r6) = T(k1) exactly.
  k_ln_gemv<<<NBLK, 256, 0, stream>>>(pairp, gamma, beta, W, bvec, x);
  k_ln_gemv<<<NBLK, 256, 0, stream>>>(pairp, gamma, beta, W, bvec, x);
  k_sym<<<dim3(32, 32), 256, 0, stream>>>(x, seq, out, rowsum);  // xs -> out
  k_lse<<<(NN * 6 + 255) / 256, 256, 0, stream>>>(rowsum, lse);
  k_out<<<NP / 256, 256, 0, stream>>>(out, lse);
}

// Round 12
// 193.250 us; speedup vs baseline: 1.2871x; 1.2871x over previous
//
#include <hip/hip_runtime.h>
#include <hip/hip_cooperative_groups.h>

namespace cg = cooperative_groups;

#define NN 1024
#define NP (NN * NN)
#define NBLK 1024
#define NGRP (NBLK * 16)   // 16384 groups, 2 pairs/group/iter -> 32 iters

typedef float f32x4 __attribute__((ext_vector_type(4)));

__device__ __forceinline__ f32x4 ntld(const float* p) {
  return __builtin_nontemporal_load((const f32x4*)p);
}

#define DPP_ADD_STAGE(v, ctrl)                                               \
  {                                                                          \
    const int _t = __builtin_amdgcn_update_dpp(                              \
        0, __float_as_int(v), (ctrl), 0xf, 0xf, true);                       \
    (v) += __int_as_float(_t);                                               \
  }

// ---------------- k1: LayerNorm + GEMV (r6-proven) + rowsum zeroing ---------
__global__ __launch_bounds__(256) void k_ln_gemv(
    const float* __restrict__ pairp, const float* __restrict__ gamma,
    const float* __restrict__ beta, const float* __restrict__ W,
    const float* __restrict__ bvec, float* __restrict__ xout,
    float* __restrict__ rowsum)
{
  if (blockIdx.x == 0) {
    for (int k = threadIdx.x; k < NN * 6; k += 256) rowsum[k] = 0.f;
  }

  const int l = threadIdx.x & 15;
  const int group = blockIdx.x * 16 + (threadIdx.x >> 4);

  float ug[8][6], apart[6] = {0, 0, 0, 0, 0, 0}, bpart[6] = {0, 0, 0, 0, 0, 0};
#pragma unroll
  for (int k = 0; k < 2; ++k)
#pragma unroll
    for (int m = 0; m < 4; ++m) {
      const int c = 4 * l + 64 * k + m;
      const int idx = 4 * k + m;
      const float ga = gamma[c], be = beta[c];
#pragma unroll
      for (int d = 0; d < 6; ++d) {
        const float w = W[c * 6 + d];
        ug[idx][d] = ga * w;
        apart[d] += ga * w;
        bpart[d] += be * w;
      }
    }
#pragma unroll
  for (int d = 0; d < 6; ++d)
#pragma unroll
    for (int m = 1; m <= 8; m <<= 1) {
      apart[d] += __shfl_xor(apart[d], m);
      bpart[d] += __shfl_xor(bpart[d], m);
    }
  const float vA = (l == 0) ? apart[0] : (l == 1) ? apart[1] : (l == 2) ? apart[2]
                  : (l == 3) ? apart[3] : (l == 4) ? apart[4] : apart[5];
  float vB = (l == 0) ? bpart[0] : (l == 1) ? bpart[1] : (l == 2) ? bpart[2]
            : (l == 3) ? bpart[3] : (l == 4) ? bpart[4] : bpart[5];
  if (l < 6) vB += bvec[l];

  size_t p = 2 * (size_t)group;
  const float* bp = pairp + p * 128 + 4 * l;
  f32x4 a0 = ntld(bp), b0 = ntld(bp + 64);
  f32x4 a1 = ntld(bp + 128), b1 = ntld(bp + 192);

  for (int it = 0; it < 32; ++it) {
    const size_t pn = p + 2 * NGRP;
    f32x4 na0, nb0, na1, nb1;
    if (it != 31) {
      const float* nbp = pairp + pn * 128 + 4 * l;
      na0 = ntld(nbp); nb0 = ntld(nbp + 64);
      na1 = ntld(nbp + 128); nb1 = ntld(nbp + 192);
    }

    const float xv0[8] = {a0.x, a0.y, a0.z, a0.w, b0.x, b0.y, b0.z, b0.w};
    const float xv1[8] = {a1.x, a1.y, a1.z, a1.w, b1.x, b1.y, b1.z, b1.w};
    float r[16];
#pragma unroll
    for (int k = 0; k < 16; ++k) r[k] = 0.f;
#pragma unroll
    for (int k = 0; k < 8; ++k) {
      r[0] += xv0[k];
      r[1] = fmaf(xv0[k], xv0[k], r[1]);
      r[8] += xv1[k];
      r[9] = fmaf(xv1[k], xv1[k], r[9]);
#pragma unroll
      for (int d = 0; d < 6; ++d) {
        r[2 + d] = fmaf(xv0[k], ug[k][d], r[2 + d]);
        r[10 + d] = fmaf(xv1[k], ug[k][d], r[10 + d]);
      }
    }
#pragma unroll
    for (int k = 0; k < 16; ++k) DPP_ADD_STAGE(r[k], 0xB1);
#pragma unroll
    for (int k = 0; k < 16; ++k) DPP_ADD_STAGE(r[k], 0x4E);
#pragma unroll
    for (int k = 0; k < 16; ++k) DPP_ADD_STAGE(r[k], 0x141);
#pragma unroll
    for (int k = 0; k < 16; ++k) DPP_ADD_STAGE(r[k], 0x140);

    if (l < 6) {
      const float mu0 = r[0] * (1.f / 128.f);
      const float var0 = r[1] * (1.f / 128.f) - mu0 * mu0;
      const float rstd0 = rsqrtf(var0 + 1e-5f);
      const float vg0 = (l == 0) ? r[2] : (l == 1) ? r[3] : (l == 2) ? r[4]
                       : (l == 3) ? r[5] : (l == 4) ? r[6] : r[7];
      xout[p * 6 + l] = fmaf(rstd0, vg0 - mu0 * vA, vB);

      const float mu1 = r[8] * (1.f / 128.f);
      const float var1 = r[9] * (1.f / 128.f) - mu1 * mu1;
      const float rstd1 = rsqrtf(var1 + 1e-5f);
      const float vg1 = (l == 0) ? r[10] : (l == 1) ? r[11] : (l == 2) ? r[12]
                       : (l == 3) ? r[13] : (l == 4) ? r[14] : r[15];
      xout[(p + 1) * 6 + l] = fmaf(rstd1, vg1 - mu1 * vA, vB);
    }
    p = pn;
    a0 = na0; b0 = nb0; a1 = na1; b1 = nb1;
  }
}

// ------- k_down2: cooperative, 512 blocks, 2 J-tiles per block --------------
// Stage mirror tile -> regs v[8][6] -> rowsum atomics -> grid.sync ->
// lse from rowsum -> out from regs. xs never materialized.
#define DO_TILE(VOFF, JT)                                                     \
  {                                                                           \
    __syncthreads();                                                          \
    const float* mb = x + ((size_t)((JT) * 32) * NN + I * 32) * 6;            \
    for (int k = tid; k < 1536; k += 256) {                                   \
      const int m = k / 48, f = k % 48;                                       \
      const float4 v4 = *(const float4*)(mb + (size_t)m * (NN * 6) + f * 4);  \
      float* dst = &M[m * 193 + f * 4];                                       \
      dst[0] = v4.x; dst[1] = v4.y; dst[2] = v4.z; dst[3] = v4.w;             \
    }                                                                         \
    __syncthreads();                                                          \
    _Pragma("unroll")                                                         \
    for (int q = 0; q < 4; ++q) {                                             \
      const int e = tid + 256 * q;                                            \
      const int r = e >> 5, c = e & 31;                                       \
      const int i = I * 32 + r, j = (JT) * 32 + c;                            \
      const int dd = seq[i] - seq[j];                                         \
      const bool far = (dd > 3) || (dd < -3);                                 \
      const float* own = x + ((size_t)i * NN + j) * 6;                        \
      const float2 o0 = *(const float2*)(own);                                \
      const float2 o1 = *(const float2*)(own + 2);                            \
      const float2 o2 = *(const float2*)(own + 4);                            \
      const float* mr = &M[c * 193 + r * 6];                                  \
      v[(VOFF) + q][0] = far ? 0.5f * (o0.x + mr[0]) : -1000000.f;            \
      v[(VOFF) + q][1] = far ? 0.5f * (o0.y + mr[1]) : -1000000.f;            \
      v[(VOFF) + q][2] = far ? 0.5f * (o1.x + mr[2]) : -1000000.f;            \
      v[(VOFF) + q][3] = far ? 0.5f * (o1.y + mr[3]) : -1000000.f;            \
      v[(VOFF) + q][4] = far ? 0.5f * (o2.x + mr[4]) : -1000000.f;            \
      v[(VOFF) + q][5] = far ? 0.5f * (o2.y + mr[5]) : -1000000.f;            \
      float ss = 0.f;                                                         \
      _Pragma("unroll")                                                       \
      for (int d = 0; d < 6; ++d) {                                           \
        const float e_ = __expf(v[(VOFF) + q][d]);                            \
        esum[q][d] += e_;                                                     \
        ss += e_;                                                             \
      }                                                                       \
      ssum[(VOFF) + q] = ss;                                                  \
    }                                                                         \
  }

__global__ __launch_bounds__(256, 4) void k_down2(
    const float* __restrict__ x, const int* __restrict__ seq,
    float* __restrict__ rowsum, float* __restrict__ out)
{
  cg::grid_group grid = cg::this_grid();
  const int Jp = blockIdx.x, I = blockIdx.y;
  const int J0 = 2 * Jp, J1 = 2 * Jp + 1;
  const int tid = threadIdx.x;
  __shared__ float M[32 * 193];
  __shared__ float LSI[192], LSJ0[192], LSJ1[192];

  float v[8][6], ssum[8], esum[4][6];
#pragma unroll
  for (int q = 0; q < 4; ++q)
#pragma unroll
    for (int d = 0; d < 6; ++d) esum[q][d] = 0.f;

  DO_TILE(0, J0)
  DO_TILE(4, J1)

  // row exp-sums over both tiles: reduce over c (32-lane halves), one atomic
#pragma unroll
  for (int q = 0; q < 4; ++q)
#pragma unroll
    for (int d = 0; d < 6; ++d)
#pragma unroll
      for (int m = 1; m <= 16; m <<= 1) esum[q][d] += __shfl_xor(esum[q][d], m);

  if ((tid & 31) == 0) {
    const int w = tid >> 5;
#pragma unroll
    for (int q = 0; q < 4; ++q) {
      const int i = I * 32 + w + 8 * q;
#pragma unroll
      for (int d = 0; d < 6; ++d) atomicAdd(&rowsum[i * 6 + d], esum[q][d]);
    }
  }

  grid.sync();  // rowsum complete

  // lse slices needed by this block: I-band, J0-band, J1-band (576 values)
  for (int k = tid; k < 576; k += 256) {
    if (k < 192) LSI[k] = logf(1.f + rowsum[I * 192 + k]);
    else if (k < 384) LSJ0[k - 192] = logf(1.f + rowsum[J0 * 192 + (k - 192)]);
    else LSJ1[k - 384] = logf(1.f + rowsum[J1 * 192 + (k - 384)]);
  }
  __syncthreads();

  // out = 4*xs - lse_i - lse_j - 2*chn_lse, straight from registers
#pragma unroll
  for (int q = 0; q < 4; ++q) {
    const int e = tid + 256 * q;
    const int r = e >> 5, c = e & 31;
    const int i = I * 32 + r;
    {
      const float lc2 = 2.f * logf(1.f + ssum[q]);
      float o[6];
#pragma unroll
      for (int d = 0; d < 6; ++d)
        o[d] = 4.f * v[q][d] - LSI[r * 6 + d] - LSJ0[c * 6 + d] - lc2;
      float* op = out + ((size_t)i * NN + (J0 * 32 + c)) * 6;
      *(float2*)(op) = make_float2(o[0], o[1]);
      *(float2*)(op + 2) = make_float2(o[2], o[3]);
      *(float2*)(op + 4) = make_float2(o[4], o[5]);
    }
    {
      const float lc2 = 2.f * logf(1.f + ssum[4 + q]);
      float o[6];
#pragma unroll
      for (int d = 0; d < 6; ++d)
        o[d] = 4.f * v[4 + q][d] - LSI[r * 6 + d] - LSJ1[c * 6 + d] - lc2;
      float* op = out + ((size_t)i * NN + (J1 * 32 + c)) * 6;
      *(float2*)(op) = make_float2(o[0], o[1]);
      *(float2*)(op + 2) = make_float2(o[2], o[3]);
      *(float2*)(op + 4) = make_float2(o[4], o[5]);
    }
  }
}

// ---------------- fallback split path (r6-proven) ---------------------------
__global__ __launch_bounds__(256) void k_sym(
    const float* __restrict__ x, const int* __restrict__ seq,
    float* __restrict__ xs, float* __restrict__ rowsum)
{
  const int J = blockIdx.x, I = blockIdx.y;
  const int tid = threadIdx.x;
  __shared__ float M[32 * 193];

  const float* mb = x + ((size_t)(J * 32) * NN + I * 32) * 6;
  for (int k = tid; k < 1536; k += 256) {
    const int m = k / 48, f = k % 48;
    const float4 v = *(const float4*)(mb + (size_t)m * (NN * 6) + f * 4);
    float* dst = &M[m * 193 + f * 4];
    dst[0] = v.x; dst[1] = v.y; dst[2] = v.z; dst[3] = v.w;
  }
  __syncthreads();

  float es[4][6];
#pragma unroll
  for (int q = 0; q < 4; ++q) {
    const int e = tid + 256 * q;
    const int r = e >> 5, c = e & 31;
    const int i = I * 32 + r, j = J * 32 + c;
    const int dd = seq[i] - seq[j];
    const bool far = (dd > 3) || (dd < -3);
    const float* own = x + ((size_t)i * NN + j) * 6;
    const float2 o0 = *(const float2*)(own);
    const float2 o1 = *(const float2*)(own + 2);
    const float2 o2 = *(const float2*)(own + 4);
    const float* mr = &M[c * 193 + r * 6];
    float v[6];
    v[0] = far ? 0.5f * (o0.x + mr[0]) : -1000000.f;
    v[1] = far ? 0.5f * (o0.y + mr[1]) : -1000000.f;
    v[2] = far ? 0.5f * (o1.x + mr[2]) : -1000000.f;
    v[3] = far ? 0.5f * (o1.y + mr[3]) : -1000000.f;
    v[4] = far ? 0.5f * (o2.x + mr[4]) : -1000000.f;
    v[5] = far ? 0.5f * (o2.y + mr[5]) : -1000000.f;
    float* op = xs + ((size_t)i * NN + j) * 6;
    *(float2*)(op) = make_float2(v[0], v[1]);
    *(float2*)(op + 2) = make_float2(v[2], v[3]);
    *(float2*)(op + 4) = make_float2(v[4], v[5]);
#pragma unroll
    for (int d = 0; d < 6; ++d) es[q][d] = __expf(v[d]);
  }

#pragma unroll
  for (int q = 0; q < 4; ++q)
#pragma unroll
    for (int d = 0; d < 6; ++d)
#pragma unroll
      for (int m = 1; m <= 16; m <<= 1) es[q][d] += __shfl_xor(es[q][d], m);

  if ((tid & 31) == 0) {
    const int w = tid >> 5;
#pragma unroll
    for (int q = 0; q < 4; ++q) {
      const int i = I * 32 + w + 8 * q;
#pragma unroll
      for (int d = 0; d < 6; ++d) atomicAdd(&rowsum[i * 6 + d], es[q][d]);
    }
  }
}

__global__ __launch_bounds__(256) void k_lse(
    const float* __restrict__ rowsum, float* __restrict__ lse)
{
  const int k = blockIdx.x * 256 + threadIdx.x;
  if (k < NN * 6) lse[k] = logf(1.0f + rowsum[k]);
}

__global__ __launch_bounds__(256) void k_out(
    float* __restrict__ out, const float* __restrict__ lse)
{
  const int p = blockIdx.x * 256 + threadIdx.x;
  const int i = p >> 10;
  const int j = p & (NN - 1);

  float* a = out + (size_t)p * 6;
  const float2 a0 = *(const float2*)(a);
  const float2 a1 = *(const float2*)(a + 2);
  const float2 a2 = *(const float2*)(a + 4);
  const float v[6] = {a0.x, a0.y, a1.x, a1.y, a2.x, a2.y};

  float ssum = 0.f;
#pragma unroll
  for (int d = 0; d < 6; ++d) ssum += __expf(v[d]);
  const float lc2 = 2.f * logf(1.f + ssum);

  const float* li = lse + i * 6;
  const float* lj = lse + j * 6;
  float o[6];
#pragma unroll
  for (int d = 0; d < 6; ++d) o[d] = 4.f * v[d] - li[d] - lj[d] - lc2;

  *(float2*)(a) = make_float2(o[0], o[1]);
  *(float2*)(a + 2) = make_float2(o[2], o[3]);
  *(float2*)(a + 4) = make_float2(o[4], o[5]);
}

extern "C" void kernel_launch(void* const* d_in, const int* in_sizes, int n_in,
                              void* d_out, int out_size, void* d_ws, size_t ws_size,
                              hipStream_t stream) {
  const float* pairp = (const float*)d_in[0];
  const int* seq = (const int*)d_in[1];
  const float* gamma = (const float*)d_in[2];
  const float* beta = (const float*)d_in[3];
  const float* W = (const float*)d_in[4];
  const float* bvec = (const float*)d_in[5];
  float* out = (float*)d_out;

  float* x = (float*)d_ws;              // raw x: 1024*1024*6 fp32 = 24 MB
  float* rowsum = x + (size_t)NP * 6;   // 1024*6
  float* lse = rowsum + NN * 6;         // 1024*6

  k_ln_gemv<<<NBLK, 256, 0, stream>>>(pairp, gamma, beta, W, bvec, x, rowsum);

  const float* xc = x;
  void* kargs[] = {(void*)&xc, (void*)&seq, (void*)&rowsum, (void*)&out};
  hipError_t err = hipLaunchCooperativeKernel(
      (const void*)k_down2, dim3(16, 32), dim3(256), kargs, 0, stream);
  if (err != hipSuccess) {
    // fallback: proven r6 split path (identical math)
    k_sym<<<dim3(32, 32), 256, 0, stream>>>(x, seq, out, rowsum);
    k_lse<<<(NN * 6 + 255) / 256, 256, 0, stream>>>(rowsum, lse);
    k_out<<<NP / 256, 256, 0, stream>>>(out, lse);
  }
}

// Round 13
// 133.464 us; speedup vs baseline: 1.8636x; 1.4480x over previous
//
#include <hip/hip_runtime.h>

#define NN 1024
#define NP (NN * NN)
#define NBLK 1024
#define NGRP (NBLK * 16)   // k1: 16384 groups, 2 pairs/group/iter -> 32 iters

typedef float f32x4 __attribute__((ext_vector_type(4)));

__device__ __forceinline__ f32x4 ntld(const float* p) {
  return __builtin_nontemporal_load((const f32x4*)p);
}

// bf16 helpers (round-to-nearest-even pack, shift unpack)
__device__ __forceinline__ ushort bfr(float f) {
  uint u = __float_as_uint(f);
  return (ushort)((u + 0x7fffu + ((u >> 16) & 1u)) >> 16);
}
__device__ __forceinline__ float ubf(uint u) {
  return __uint_as_float(u << 16);
}

#define DPP_ADD_STAGE(v, ctrl)                                               \
  {                                                                          \
    const int _t = __builtin_amdgcn_update_dpp(                              \
        0, __float_as_int(v), (ctrl), 0xf, 0xf, true);                       \
    (v) += __int_as_float(_t);                                               \
  }

// ---------------- k1: LayerNorm + GEMV (r6-proven math), bf16 x out ---------
__global__ __launch_bounds__(256) void k_ln_gemv(
    const float* __restrict__ pairp, const float* __restrict__ gamma,
    const float* __restrict__ beta, const float* __restrict__ W,
    const float* __restrict__ bvec, ushort* __restrict__ xout,
    float* __restrict__ rowsum)
{
  if (blockIdx.x == 0) {
    for (int k = threadIdx.x; k < NN * 6; k += 256) rowsum[k] = 0.f;
  }

  const int l = threadIdx.x & 15;
  const int group = blockIdx.x * 16 + (threadIdx.x >> 4);

  float ug[8][6], apart[6] = {0, 0, 0, 0, 0, 0}, bpart[6] = {0, 0, 0, 0, 0, 0};
#pragma unroll
  for (int k = 0; k < 2; ++k)
#pragma unroll
    for (int m = 0; m < 4; ++m) {
      const int c = 4 * l + 64 * k + m;
      const int idx = 4 * k + m;
      const float ga = gamma[c], be = beta[c];
#pragma unroll
      for (int d = 0; d < 6; ++d) {
        const float w = W[c * 6 + d];
        ug[idx][d] = ga * w;
        apart[d] += ga * w;
        bpart[d] += be * w;
      }
    }
#pragma unroll
  for (int d = 0; d < 6; ++d)
#pragma unroll
    for (int m = 1; m <= 8; m <<= 1) {
      apart[d] += __shfl_xor(apart[d], m);
      bpart[d] += __shfl_xor(bpart[d], m);
    }
  const float vA = (l == 0) ? apart[0] : (l == 1) ? apart[1] : (l == 2) ? apart[2]
                  : (l == 3) ? apart[3] : (l == 4) ? apart[4] : apart[5];
  float vB = (l == 0) ? bpart[0] : (l == 1) ? bpart[1] : (l == 2) ? bpart[2]
            : (l == 3) ? bpart[3] : (l == 4) ? bpart[4] : bpart[5];
  if (l < 6) vB += bvec[l];

  size_t p = 2 * (size_t)group;
  const float* bp = pairp + p * 128 + 4 * l;
  f32x4 a0 = ntld(bp), b0 = ntld(bp + 64);
  f32x4 a1 = ntld(bp + 128), b1 = ntld(bp + 192);

  for (int it = 0; it < 32; ++it) {
    const size_t pn = p + 2 * NGRP;
    f32x4 na0, nb0, na1, nb1;
    if (it != 31) {
      const float* nbp = pairp + pn * 128 + 4 * l;
      na0 = ntld(nbp); nb0 = ntld(nbp + 64);
      na1 = ntld(nbp + 128); nb1 = ntld(nbp + 192);
    }

    const float xv0[8] = {a0.x, a0.y, a0.z, a0.w, b0.x, b0.y, b0.z, b0.w};
    const float xv1[8] = {a1.x, a1.y, a1.z, a1.w, b1.x, b1.y, b1.z, b1.w};
    float r[16];
#pragma unroll
    for (int k = 0; k < 16; ++k) r[k] = 0.f;
#pragma unroll
    for (int k = 0; k < 8; ++k) {
      r[0] += xv0[k];
      r[1] = fmaf(xv0[k], xv0[k], r[1]);
      r[8] += xv1[k];
      r[9] = fmaf(xv1[k], xv1[k], r[9]);
#pragma unroll
      for (int d = 0; d < 6; ++d) {
        r[2 + d] = fmaf(xv0[k], ug[k][d], r[2 + d]);
        r[10 + d] = fmaf(xv1[k], ug[k][d], r[10 + d]);
      }
    }
#pragma unroll
    for (int k = 0; k < 16; ++k) DPP_ADD_STAGE(r[k], 0xB1);
#pragma unroll
    for (int k = 0; k < 16; ++k) DPP_ADD_STAGE(r[k], 0x4E);
#pragma unroll
    for (int k = 0; k < 16; ++k) DPP_ADD_STAGE(r[k], 0x141);
#pragma unroll
    for (int k = 0; k < 16; ++k) DPP_ADD_STAGE(r[k], 0x140);

    if (l < 6) {
      const float mu0 = r[0] * (1.f / 128.f);
      const float var0 = r[1] * (1.f / 128.f) - mu0 * mu0;
      const float rstd0 = rsqrtf(var0 + 1e-5f);
      const float vg0 = (l == 0) ? r[2] : (l == 1) ? r[3] : (l == 2) ? r[4]
                       : (l == 3) ? r[5] : (l == 4) ? r[6] : r[7];
      xout[p * 6 + l] = bfr(fmaf(rstd0, vg0 - mu0 * vA, vB));

      const float mu1 = r[8] * (1.f / 128.f);
      const float var1 = r[9] * (1.f / 128.f) - mu1 * mu1;
      const float rstd1 = rsqrtf(var1 + 1e-5f);
      const float vg1 = (l == 0) ? r[10] : (l == 1) ? r[11] : (l == 2) ? r[12]
                       : (l == 3) ? r[13] : (l == 4) ? r[14] : r[15];
      xout[(p + 1) * 6 + l] = bfr(fmaf(rstd1, vg1 - mu1 * vA, vB));
    }
    p = pn;
    a0 = na0; b0 = nb0; a1 = na1; b1 = nb1;
  }
}

// -------- k_sym2: triangular blocks, each x tile staged exactly once --------
// Block b -> (I,J), J<=I. Stages x[I-band][J-band] (M1) and x[J-band][I-band]
// (M2, ==M1 on diagonal). Emits t = 4*xs - 2*chn_lse (bf16) for BOTH
// orientations + row exp-sum atomics.
__device__ __forceinline__ void do_tile(
    const float* __restrict__ Mr, const float* __restrict__ Mc,
    int rowBand, int colBand, const int* __restrict__ seq,
    ushort* __restrict__ t, float* __restrict__ rowsum, int tid)
{
  float es[4][6];
#pragma unroll
  for (int q = 0; q < 4; ++q) {
    const int e = tid + 256 * q;
    const int r = e >> 5, c = e & 31;
    const int i = rowBand + r, j = colBand + c;
    const int dd = seq[i] - seq[j];
    const bool far = (dd > 3) || (dd < -3);
    const float* mr = &Mr[r * 193 + c * 6];
    const float* mc = &Mc[c * 193 + r * 6];
    float xs[6], chs = 0.f;
#pragma unroll
    for (int d = 0; d < 6; ++d) {
      xs[d] = far ? 0.5f * (mr[d] + mc[d]) : -1000000.f;
      es[q][d] = __expf(xs[d]);
      chs += es[q][d];
    }
    const float c2 = 2.f * logf(1.f + chs);
    uint w0 = (uint)bfr(4.f * xs[0] - c2) | ((uint)bfr(4.f * xs[1] - c2) << 16);
    uint w1 = (uint)bfr(4.f * xs[2] - c2) | ((uint)bfr(4.f * xs[3] - c2) << 16);
    uint w2 = (uint)bfr(4.f * xs[4] - c2) | ((uint)bfr(4.f * xs[5] - c2) << 16);
    uint* tp = (uint*)(t + ((size_t)i * NN + j) * 6);
    tp[0] = w0; tp[1] = w1; tp[2] = w2;
  }
#pragma unroll
  for (int q = 0; q < 4; ++q)
#pragma unroll
    for (int d = 0; d < 6; ++d)
#pragma unroll
      for (int m = 1; m <= 16; m <<= 1) es[q][d] += __shfl_xor(es[q][d], m);
  if ((tid & 31) == 0) {
    const int w = tid >> 5;
#pragma unroll
    for (int q = 0; q < 4; ++q) {
      const int i = rowBand + w + 8 * q;
#pragma unroll
      for (int d = 0; d < 6; ++d) atomicAdd(&rowsum[i * 6 + d], es[q][d]);
    }
  }
}

__global__ __launch_bounds__(256) void k_sym2(
    const ushort* __restrict__ x, const int* __restrict__ seq,
    ushort* __restrict__ t, float* __restrict__ rowsum)
{
  const int b = blockIdx.x;
  int I = (int)((sqrtf(8.f * b + 1.f) - 1.f) * 0.5f);
  while ((I + 1) * (I + 2) / 2 <= b) ++I;
  while (I * (I + 1) / 2 > b) --I;
  const int J = b - I * (I + 1) / 2;  // J <= I
  const int tid = threadIdx.x;

  __shared__ float M1[32 * 193];  // x[I-band][J-band]
  __shared__ float M2[32 * 193];  // x[J-band][I-band]

  // stage: 768 chunks of 8 bf16 (16B) per tile
  for (int k = tid; k < 768; k += 256) {
    const int m = k / 24, f = (k % 24) * 8;
    {
      const uint4 raw = *(const uint4*)(x + ((size_t)(I * 32 + m) * NN + J * 32) * 6 + f);
      float* dst = &M1[m * 193 + f];
      dst[0] = ubf(raw.x & 0xffff); dst[1] = ubf(raw.x >> 16);
      dst[2] = ubf(raw.y & 0xffff); dst[3] = ubf(raw.y >> 16);
      dst[4] = ubf(raw.z & 0xffff); dst[5] = ubf(raw.z >> 16);
      dst[6] = ubf(raw.w & 0xffff); dst[7] = ubf(raw.w >> 16);
    }
    if (I != J) {
      const uint4 raw = *(const uint4*)(x + ((size_t)(J * 32 + m) * NN + I * 32) * 6 + f);
      float* dst = &M2[m * 193 + f];
      dst[0] = ubf(raw.x & 0xffff); dst[1] = ubf(raw.x >> 16);
      dst[2] = ubf(raw.y & 0xffff); dst[3] = ubf(raw.y >> 16);
      dst[4] = ubf(raw.z & 0xffff); dst[5] = ubf(raw.z >> 16);
      dst[6] = ubf(raw.w & 0xffff); dst[7] = ubf(raw.w >> 16);
    }
  }
  __syncthreads();

  if (I != J) {
    do_tile(M1, M2, I * 32, J * 32, seq, t, rowsum, tid);  // orientation (I,J)
    do_tile(M2, M1, J * 32, I * 32, seq, t, rowsum, tid);  // orientation (J,I)
  } else {
    do_tile(M1, M1, I * 32, J * 32, seq, t, rowsum, tid);  // diagonal
  }
}

// -------- k_out2: out = t - lse_i - lse_j (lse = log1p(rowsum), on the fly) --
__global__ __launch_bounds__(256) void k_out2(
    const ushort* __restrict__ t, const float* __restrict__ rowsum,
    float* __restrict__ out)
{
  const int b = blockIdx.x;
  const int i = b >> 2;
  const int j = ((b & 3) << 8) + threadIdx.x;

  __shared__ float LSI[6];
  if (threadIdx.x < 6) LSI[threadIdx.x] = logf(1.f + rowsum[i * 6 + threadIdx.x]);
  __syncthreads();

  float lj[6];
#pragma unroll
  for (int d = 0; d < 6; ++d) lj[d] = logf(1.f + rowsum[j * 6 + d]);

  const size_t p = (size_t)i * NN + j;
  const uint* tp = (const uint*)(t + p * 6);
  const uint w0 = tp[0], w1 = tp[1], w2 = tp[2];
  float o[6];
  o[0] = ubf(w0 & 0xffff) - LSI[0] - lj[0];
  o[1] = ubf(w0 >> 16)    - LSI[1] - lj[1];
  o[2] = ubf(w1 & 0xffff) - LSI[2] - lj[2];
  o[3] = ubf(w1 >> 16)    - LSI[3] - lj[3];
  o[4] = ubf(w2 & 0xffff) - LSI[4] - lj[4];
  o[5] = ubf(w2 >> 16)    - LSI[5] - lj[5];

  float* op = out + p * 6;
  *(float2*)(op) = make_float2(o[0], o[1]);
  *(float2*)(op + 2) = make_float2(o[2], o[3]);
  *(float2*)(op + 4) = make_float2(o[4], o[5]);
}

extern "C" void kernel_launch(void* const* d_in, const int* in_sizes, int n_in,
                              void* d_out, int out_size, void* d_ws, size_t ws_size,
                              hipStream_t stream) {
  const float* pairp = (const float*)d_in[0];
  const int* seq = (const int*)d_in[1];
  const float* gamma = (const float*)d_in[2];
  const float* beta = (const float*)d_in[3];
  const float* W = (const float*)d_in[4];
  const float* bvec = (const float*)d_in[5];
  float* out = (float*)d_out;

  ushort* x = (ushort*)d_ws;                   // bf16 x: 12 MB
  ushort* t = x + (size_t)NP * 6;              // bf16 t: 12 MB
  float* rowsum = (float*)(t + (size_t)NP * 6);  // 24 KB

  k_ln_gemv<<<NBLK, 256, 0, stream>>>(pairp, gamma, beta, W, bvec, x, rowsum);
  k_sym2<<<528, 256, 0, stream>>>(x, seq, t, rowsum);
  k_out2<<<NP / 256, 256, 0, stream>>>(t, rowsum, out);
}